// Round 4
// baseline (326.164 us; speedup 1.0000x reference)
//
#include <hip/hip_runtime.h>
#include <stdint.h>
#include <math.h>

// out = relu( tile(pool2(x1),2) + tile(pool4(x2),4) + tile(pool8(x3),8)
//             + tile(pool16(x4),16) + ff )   all NCHW fp32, B=16, out 16x256x24x24.
//
// Round-7: global_load_lds DMA pipeline (registers removed from the load path).
// Evidence r3-r6: 285,696 wave-loads, 116+-3us, ~2TB/s at ANY occupancy; compiler
// defeats register-staged MLP every time (hoists consume VALU between asm loads,
// VGPR 32/48/68). Fix: fire-and-forget global->LDS DMA (no dest regs -> nothing
// to rebalance), persistent blocks, double-buffered tiles, counted per-wave
// vmcnt waits so the next tile's stream stays in flight across barriers
// (T3 2-phase template, m97/m201-verified path).
//
// 256 blocks (1/CU) x 512 threads, 18 tiles each (tile = b,oh,2 output cols).
// Per tile: 60KB raw (A4+B8+C16+D32 KB) + 2KB ff staged by 61 DMA instrs.
// Per-wave per tile: 1 ff dma4 + {8|7} dma16 segs -> WAIT_A = vmcnt(9|8).

namespace {

__device__ __forceinline__ void dma16(const float* g, float* l) {
  __builtin_amdgcn_global_load_lds(
      (const __attribute__((address_space(1))) uint32_t*)(const void*)g,
      (__attribute__((address_space(3))) uint32_t*)(void*)l, 16, 0, 0);
}
__device__ __forceinline__ void dma4(const float* g, float* l) {
  __builtin_amdgcn_global_load_lds(
      (const __attribute__((address_space(1))) uint32_t*)(const void*)g,
      (__attribute__((address_space(3))) uint32_t*)(void*)l, 4, 0, 0);
}

#define WAITV(n)                                                \
  do {                                                          \
    asm volatile("s_waitcnt vmcnt(" #n ")" ::: "memory");       \
    __builtin_amdgcn_sched_barrier(0);                          \
  } while (0)

#define BARRIER()                                               \
  do {                                                          \
    asm volatile("" ::: "memory");                              \
    __builtin_amdgcn_s_barrier();                               \
    asm volatile("" ::: "memory");                              \
  } while (0)

__device__ __forceinline__ float fmax4(const float4 v) {
  return fmaxf(fmaxf(v.x, v.y), fmaxf(v.z, v.w));
}
__device__ __forceinline__ float4 max4(const float4 a, const float4 b) {
  float4 r;
  r.x = fmaxf(a.x, b.x); r.y = fmaxf(a.y, b.y);
  r.z = fmaxf(a.z, b.z); r.w = fmaxf(a.w, b.w);
  return r;
}

__global__ __launch_bounds__(512, 1) void fused_dma(const float* __restrict__ x1,
                                                    const float* __restrict__ x2,
                                                    const float* __restrict__ x3,
                                                    const float* __restrict__ x4,
                                                    const float* __restrict__ ffp,
                                                    float* __restrict__ out) {
  // Raw staging: [A 1024f][B 2048f][C 4096f][D 8192f] = 15360 floats = 60KB.
  __shared__ float buf[2][15360];
  __shared__ float ffl[2][512];
  // Pooled (transposed [w][ch]); single-buffered, guarded by BAR1..BAR3.
  __shared__ float s1t[2 * 128];
  __shared__ float s2t[2 * 64];
  __shared__ float s3t[2 * 32];
  __shared__ float s4t[2 * 16];

  const int cid  = blockIdx.x;    // 0..255 (persistent, 1/CU)
  const int tid  = threadIdx.x;   // 0..511
  const int wv   = tid >> 6;      // wave 0..7
  const int lane = tid & 63;

  // Issue all DMA for tile tt into buffer bi. Per-wave: 1 dma4 + {8|7} dma16,
  // ascending seg order (last issued = D region).
  auto stage = [&](int tt, int bi) {
    const int b = tt / 288, rem = tt % 288, oh = rem / 12, cp = rem % 12;
    const size_t bA = (size_t)b * 294912  + oh * 96   + cp * 4;
    const size_t bB = (size_t)b * 589824  + oh * 384  + cp * 8;
    const size_t bC = (size_t)b * 1179648 + oh * 1536 + cp * 16;
    const size_t bD = (size_t)b * 2359296 + oh * 6144 + cp * 32;
    const size_t bF = (size_t)b * 147456  + oh * 24   + cp * 2;
    {  // ff: 512 floats, 1 dma4 per wave. ffl[j] = ff[c=j>>1][col=j&1]
      const int j = wv * 64 + lane;
      dma4(ffp + bF + (size_t)(j >> 1) * 576 + (j & 1), &ffl[bi][wv * 64]);
    }
    for (int s = wv; s < 60; s += 8) {  // 1KB segments; region uniform per s
      const float* g;
      if (s < 4) {         // A: 16B per (ch,row): i=ch*2+row
        const int i = s * 64 + lane;
        g = x1 + bA + (size_t)(i >> 1) * 2304 + (i & 1) * 48;
      } else if (s < 12) { // B: 32B per (ch,row)
        const int i = (s - 4) * 64 + lane;
        g = x2 + bB + (size_t)(i >> 3) * 9216 + ((i >> 1) & 3) * 96 + (i & 1) * 4;
      } else if (s < 28) { // C: 64B per (ch,row)
        const int i = (s - 12) * 64 + lane;
        g = x3 + bC + (size_t)(i >> 5) * 36864 + ((i >> 2) & 7) * 192 + (i & 3) * 4;
      } else {             // D: 128B per (ch,row)
        const int i = (s - 28) * 64 + lane;
        g = x4 + bD + (size_t)(i >> 7) * 147456 + ((i >> 3) & 15) * 384 + (i & 7) * 4;
      }
      dma16(g, &buf[bi][s * 256]);
    }
  };

  stage(cid, 0);  // prologue: tile t0 -> buffer 0

  for (int i = 0; i < 18; ++i) {
    const int t   = i * 256 + cid;
    const int cur = i & 1;
    const int b = t / 288, rem = t % 288, oh = rem / 12, cp = rem % 12;

    if (i < 17) stage(t + 256, cur ^ 1);

    // WAIT_A: tile t's loads (per-wave) retired; t+1's stream stays in flight.
    // Younger loads than last seg(t): ff(t+1) + nseg(t+1) = 9 (wv<4) | 8 (wv>=4).
    if (i < 17) {
      if (wv < 4) WAITV(9); else WAITV(8);
    } else {
      WAITV(0);
    }
    BARRIER();  // BAR1: all waves' tile-t DMA landed

    // ---- R1: pool raw -> transposed pooled tiles ----
    {
      const float* Bv = &buf[cur][0];
      if (tid < 256) {            // A: ch(128) x w(2); 2x float2
        const int ch = tid >> 1, w = tid & 1;
        const float2 r0 = *reinterpret_cast<const float2*>(&Bv[ch * 8 + w * 2]);
        const float2 r1 = *reinterpret_cast<const float2*>(&Bv[ch * 8 + 4 + w * 2]);
        s1t[w * 128 + ch] = fmaxf(fmaxf(r0.x, r0.y), fmaxf(r1.x, r1.y));
      } else if (tid < 384) {     // B: ch(64) x w(2); 4x float4
        const int j = tid - 256, ch = j >> 1, w = j & 1;
        const float* p = &Bv[1024 + ch * 32 + w * 4];
        float4 m = *reinterpret_cast<const float4*>(p);
        m = max4(m, *reinterpret_cast<const float4*>(p + 8));
        m = max4(m, *reinterpret_cast<const float4*>(p + 16));
        m = max4(m, *reinterpret_cast<const float4*>(p + 24));
        s2t[w * 64 + ch] = fmax4(m);
      } else {                    // C: ch(32) x w(2) x hf(2); 8x float4 + shfl
        const int j = tid - 384, ch = j >> 2, w = (j >> 1) & 1, hf = j & 1;
        const float* p = &Bv[3072 + ch * 128 + w * 8 + hf * 4];
        float4 m = *reinterpret_cast<const float4*>(p);
#pragma unroll
        for (int r = 1; r < 8; ++r)
          m = max4(m, *reinterpret_cast<const float4*>(p + r * 16));
        float mm = fmax4(m);
        mm = fmaxf(mm, __shfl_xor(mm, 1));
        if (hf == 0) s3t[w * 32 + ch] = mm;
      }
      if (tid < 128) {            // D (2nd task): ch(16) x w(2) x q(4); 16x float4
        const int ch = tid >> 3, w = (tid >> 2) & 1, q = tid & 3;
        const float* p = &Bv[7168 + ch * 512 + w * 16 + q * 4];
        float4 m = *reinterpret_cast<const float4*>(p);
#pragma unroll
        for (int r = 1; r < 16; ++r)
          m = max4(m, *reinterpret_cast<const float4*>(p + r * 32));
        float mm = fmax4(m);
        mm = fmaxf(mm, __shfl_xor(mm, 1));
        mm = fmaxf(mm, __shfl_xor(mm, 2));
        if (q == 0) s4t[w * 16 + ch] = mm;
      }
    }

    asm volatile("s_waitcnt lgkmcnt(0)" ::: "memory");
    __builtin_amdgcn_sched_barrier(0);
    BARRIER();  // BAR2: pooled tiles visible

    // ---- R2: combine + relu + store. (c,w) = (tid>>1, tid&1) ----
    {
      const int c = tid >> 1, w = tid & 1;
      float v = s1t[w * 128 + (c & 127)] + s2t[w * 64 + (c & 63)]
              + s3t[w * 32 + (c & 31)]  + s4t[w * 16 + (c & 15)]
              + ffl[cur][tid];
      out[(size_t)b * 147456 + (size_t)c * 576 + oh * 24 + cp * 2 + w] =
          fmaxf(v, 0.0f);
    }

    BARRIER();  // BAR3: R2 reads done before next iter's DMA overwrites cur^1
  }
}

}  // namespace

extern "C" void kernel_launch(void* const* d_in, const int* in_sizes, int n_in,
                              void* d_out, int out_size, void* d_ws, size_t ws_size,
                              hipStream_t stream) {
  const float* x1 = (const float*)d_in[0];  // [16,128,48,48]
  const float* x2 = (const float*)d_in[1];  // [16,64,96,96]
  const float* x3 = (const float*)d_in[2];  // [16,32,192,192]
  const float* x4 = (const float*)d_in[3];  // [16,16,384,384]
  const float* ff = (const float*)d_in[4];  // [16,256,24,24]
  float* out = (float*)d_out;               // [16,256,24,24]
  (void)d_ws; (void)ws_size; (void)in_sizes; (void)n_in; (void)out_size;

  fused_dma<<<256, 512, 0, stream>>>(x1, x2, x3, x4, ff, out);
}